// Round 8
// baseline (72.258 us; speedup 1.0000x reference)
//
#include <hip/hip_runtime.h>
#include <math.h>

// Problem constants: bs=32, en=256, dx=512, dz=256, heads=8, dh=32, L=1280.
//
// Mask is block-diagonal eyes: q<256 -> one-hot row; q=256+j -> exactly 4
// nonzeros {q, 512+j, 768+j, 1024+j} = col 256+j of centered state and col j
// of each centered obs. Wk folded into the query side; pe-dot and bk-dot are
// constant across the 4 softmax candidates -> cancel (shift invariance).
// Needed per (b,j,h):  dR_m = sum_e raw_m*w,  dO = sum_e w,
// with w = wu[j,h,e] + wv[b,h,e].
//
// Pipeline (4 launches): k_uv -> k_w -> k_part (latency-bound dot, partials)
// -> k_out (pure streaming: finalize softmax + all output writes).
//
// ws layout (floats): u[256][256]@0, v[32][256]@65536, wu2[8][256e][256j]@73728,
// wv[32][8][256e]@598016, pws[16jt][32b][2eq][44k][16jl]@663552.

// ---------------------------------------------------------------- k_uv
// blocks 0..255  : j-block -> u[j][f] = Q[256+j]@Wq
// blocks 256..287: b-block -> v[b][f] = pe[b]@Wq + bq (pe built in LDS only)
__global__ void k_uv(const float* __restrict__ Q, const float* __restrict__ Wq,
                     const float* __restrict__ bq,
                     float* __restrict__ u, float* __restrict__ v) {
  __shared__ float row[256];
  const int f = threadIdx.x;
  const int blk = blockIdx.x;
  float rv;
  if (blk < 256) {
    rv = Q[(256 + blk) * 256 + f];
  } else {
    const int b = blk - 256;
    // sinusoidal PE over the BATCH axis (faithful quirk): pos=b, d_model=256
    const float dv = expf(-9.210340371976184f * (float)((f >> 1) << 1) * (1.0f / 256.0f));
    const float ang = (float)b * dv;
    rv = (f & 1) ? cosf(ang) : sinf(ang);
  }
  row[f] = rv;
  __syncthreads();
  float acc = (blk < 256) ? 0.0f : bq[f];
  for (int e = 0; e < 256; ++e) acc += row[e] * Wq[e * 256 + f];
  if (blk < 256) u[blk * 256 + f] = acc;
  else           v[(blk - 256) * 256 + f] = acc;
}

// ---------------------------------------------------------------- k_w
__global__ void k_w(const float* __restrict__ Wk, const float* __restrict__ u,
                    const float* __restrict__ v, float* __restrict__ wu2,
                    float* __restrict__ wv) {
  __shared__ float wrow[256];
  const int e = blockIdx.x;
  const int t = threadIdx.x;
  wrow[t] = Wk[e * 256 + t];
  __syncthreads();
  if (blockIdx.y == 0) {
    const float* ur = u + t * 256;
#pragma unroll
    for (int h = 0; h < 8; ++h) {
      float acc = 0.0f;
#pragma unroll
      for (int d = 0; d < 32; ++d) acc += ur[h * 32 + d] * wrow[h * 32 + d];
      wu2[(h * 256 + e) * 256 + t] = acc;
    }
  } else if (t < 32) {
    const float* vr = v + t * 256;
#pragma unroll
    for (int h = 0; h < 8; ++h) {
      float acc = 0.0f;
#pragma unroll
      for (int d = 0; d < 32; ++d) acc += vr[h * 32 + d] * wrow[h * 32 + d];
      wv[(t * 8 + h) * 256 + e] = acc;
    }
  }
}

// ---------------------------------------------------------------- k_part
// grid (16 jt, 2 eq, 32 b), 512 threads = 8 waves (round-6 verbatim).
// t = jl(0..15) + 16*es(0..15) + 256*hp(0..1). Lane owns j = jt*16+jl,
// e in [eq*128 + es*8, +8), heads h = hp*4 .. hp*4+3.
__global__ __launch_bounds__(512)
void k_part(const float* __restrict__ state, const float* __restrict__ o0,
            const float* __restrict__ o1, const float* __restrict__ o2,
            const float* __restrict__ wu2, const float* __restrict__ wv,
            float* __restrict__ pws) {
  const int t = threadIdx.x;
  const int jl = t & 15;
  const int es = (t >> 4) & 15;    // 0..15
  const int hp = t >> 8;           // 0..1
  const int jt = blockIdx.x;       // 0..15
  const int eq = blockIdx.y;       // 0..1
  const int b  = blockIdx.z;       // 0..31
  const int j = jt * 16 + jl;

  __shared__ float s_wv[1024];     // [h][128]  (this eq's e-slice)
  __shared__ float s_part[8][16][25];

  for (int i = t; i < 1024; i += 512)
    s_wv[i] = wv[b * 2048 + (i >> 7) * 256 + eq * 128 + (i & 127)];
  __syncthreads();

  // acc[hh*5+c]: c=0..3 dR(state,o0,o1,o2), c=4 dO(ones); 20..23 raw sums
  float acc[24];
#pragma unroll
  for (int k = 0; k < 24; ++k) acc[k] = 0.f;

  const float* ps = state + (size_t)b * 256 * 512 + 256 + j;
  const float* p0 = o0 + (size_t)b * 256 * 256 + j;
  const float* p1 = o1 + (size_t)b * 256 * 256 + j;
  const float* p2 = o2 + (size_t)b * 256 * 256 + j;
  const float* pwu = wu2 + (size_t)hp * 4 * 256 * 256 + j;  // + (hh*256+e)*256
  const float* pwv = s_wv + hp * 4 * 128;                   // + hh*128+el

#pragma unroll
  for (int it = 0; it < 8; ++it) {
    const int el = es * 8 + it;    // 0..127 within this eq slice
    const int e = eq * 128 + el;   // global e
    const float s  = ps[(size_t)e * 512];
    const float x0 = p0[(size_t)e * 256];
    const float x1 = p1[(size_t)e * 256];
    const float x2 = p2[(size_t)e * 256];
    acc[20] += s; acc[21] += x0; acc[22] += x1; acc[23] += x2;
#pragma unroll
    for (int hh = 0; hh < 4; ++hh) {
      const float w = pwu[(size_t)(hh * 256 + e) * 256] + pwv[hh * 128 + el];
      acc[hh * 5 + 0] += s * w;  acc[hh * 5 + 1] += x0 * w;
      acc[hh * 5 + 2] += x1 * w; acc[hh * 5 + 3] += x2 * w;
      acc[hh * 5 + 4] += w;
    }
  }

  // reduce over es low bits (lane bits 4,5)
#pragma unroll
  for (int k = 0; k < 24; ++k) {
    acc[k] += __shfl_xor(acc[k], 16);
    acc[k] += __shfl_xor(acc[k], 32);
  }
  if ((t & 48) == 0) {
    const int w = t >> 6;          // 0..7
    float* p = &s_part[w][jl][0];
#pragma unroll
    for (int k = 0; k < 24; ++k) p[k] = acc[k];
  }
  __syncthreads();

  // record layout: k = h*5+c for h<8 (0..39), raw sums at 40..43
  const size_t base = (((size_t)(jt * 32 + b)) * 2 + eq) * 704;
  if (t < 16) {
#pragma unroll
    for (int k = 0; k < 20; ++k) {
      float s = s_part[0][t][k] + s_part[1][t][k] + s_part[2][t][k] + s_part[3][t][k];
      pws[base + k * 16 + t] = s;
    }
#pragma unroll
    for (int c = 0; c < 4; ++c) {
      float s = s_part[0][t][20 + c] + s_part[1][t][20 + c] +
                s_part[2][t][20 + c] + s_part[3][t][20 + c];
      pws[base + (40 + c) * 16 + t] = s;
    }
  } else if (t >= 256 && t < 272) {
    const int l = t & 15;
#pragma unroll
    for (int k = 0; k < 20; ++k) {
      float s = s_part[4][l][k] + s_part[5][l][k] + s_part[6][l][k] + s_part[7][l][k];
      pws[base + (20 + k) * 16 + l] = s;
    }
  }
}

// ---------------------------------------------------------------- k_out
// All-streaming output kernel. Roles by blockIdx.x:
//   A [0,512):    (jt,b): sum 2 eq-partials, softmax (16 lanes), then write
//                 out0 cols 256+j and out1 sparse rows q=256+j.
//   B [512,1536): out0[b][e][0:256] = state copy.
//   C [1536,2560): out1 one-hot rows q<256.
__global__ __launch_bounds__(512)
void k_out(const float* __restrict__ state, const float* __restrict__ o0,
           const float* __restrict__ o1, const float* __restrict__ o2,
           const float* __restrict__ pws, float* __restrict__ out0,
           float* __restrict__ out1) {
  const int blk = blockIdx.x;
  const int t = threadIdx.x;

  if (blk < 512) {
    const int jt = blk & 15;
    const int b  = blk >> 4;
    __shared__ float s_tot[704];   // [44k][16jl] flat
    __shared__ float s_a[16][4];

    const size_t base = ((size_t)(jt * 32 + b)) * 1408;  // 2 records of 704
    for (int i = t; i < 704; i += 512)
      s_tot[i] = pws[base + i] + pws[base + 704 + i];
    __syncthreads();

    if (t < 16) {
      float tot[44];
#pragma unroll
      for (int k = 0; k < 44; ++k) tot[k] = s_tot[k * 16 + t];
      const float m0 = tot[40] * (1.f / 256.f), m1 = tot[41] * (1.f / 256.f);
      const float m2 = tot[42] * (1.f / 256.f), m3 = tot[43] * (1.f / 256.f);
      const float inv = 0.17677669529663687f;  // 1/sqrt(32)
      float am0 = 0.f, am1 = 0.f, am2 = 0.f, am3 = 0.f;
#pragma unroll
      for (int h = 0; h < 8; ++h) {
        const float dO = tot[h * 5 + 4];
        const float s0 = (tot[h * 5 + 0] - m0 * dO) * inv;
        const float s1 = (tot[h * 5 + 1] - m1 * dO) * inv;
        const float s2 = (tot[h * 5 + 2] - m2 * dO) * inv;
        const float s3 = (tot[h * 5 + 3] - m3 * dO) * inv;
        const float mx = fmaxf(fmaxf(s0, s1), fmaxf(s2, s3));
        const float e0 = expf(s0 - mx), e1 = expf(s1 - mx);
        const float e2 = expf(s2 - mx), e3 = expf(s3 - mx);
        const float r = 1.f / (e0 + e1 + e2 + e3);
        am0 += e0 * r; am1 += e1 * r; am2 += e2 * r; am3 += e3 * r;
      }
      s_a[t][0] = am0 * 0.125f; s_a[t][1] = am1 * 0.125f;
      s_a[t][2] = am2 * 0.125f; s_a[t][3] = am3 * 0.125f;
    }
    __syncthreads();

    // ---- out0[b][e][256+j]
    {
      const int jl2 = t & 15;
      const int er = t >> 4;       // 0..31
      const float a0 = s_a[jl2][0], a1 = s_a[jl2][1];
      const float a2 = s_a[jl2][2], a3 = s_a[jl2][3];
      const int jj = jt * 16 + jl2;
#pragma unroll
      for (int k = 0; k < 8; ++k) {
        const int e = er + 32 * k;
        const size_t idxS = ((size_t)(b * 256 + e)) * 512 + 256 + jj;
        const size_t idxO = ((size_t)(b * 256 + e)) * 256 + jj;
        out0[idxS] = a0 * state[idxS] + a1 * o0[idxO] + a2 * o1[idxO] + a3 * o2[idxO];
      }
    }

    // ---- out1 rows q = 256+j (4 sparse values, rest zero)
    {
      const int r = t >> 5;        // 0..15 (row within tile)
      const int c = t & 31;
      const int j3 = jt * 16 + r;
      const int q = 256 + j3;
      const int comp = j3 & 3;
      const int tc0 = (256 + j3) >> 2, tc1 = (512 + j3) >> 2;
      const int tc2 = (768 + j3) >> 2, tc3 = (1024 + j3) >> 2;
      const float av0 = s_a[r][0], av1 = s_a[r][1];
      const float av2 = s_a[r][2], av3 = s_a[r][3];
      float4* orow = (float4*)(out1 + ((size_t)(b * 512 + q)) * 1280);
#pragma unroll
      for (int k = 0; k < 10; ++k) {
        const int c4 = c + 32 * k;
        float4 o = make_float4(0.f, 0.f, 0.f, 0.f);
        float val = 0.f; bool hit = false;
        if (c4 == tc0)      { val = av0; hit = true; }
        else if (c4 == tc1) { val = av1; hit = true; }
        else if (c4 == tc2) { val = av2; hit = true; }
        else if (c4 == tc3) { val = av3; hit = true; }
        if (hit) {
          if (comp == 0) o.x = val; else if (comp == 1) o.y = val;
          else if (comp == 2) o.z = val; else o.w = val;
        }
        orow[c4] = o;
      }
    }
  } else if (blk < 1536) {
    // ================= role B: out0[b][e][0:256] = state copy ===========
    const int i2 = blk - 512;      // 0..1023
    const int b = i2 >> 5, eg = i2 & 31;
    const int row = t >> 6;        // 0..7
    const int col = (t & 63) << 2;
    const int e = eg * 8 + row;
    const size_t base = ((size_t)(b * 256 + e)) * 512 + col;
    *(float4*)(out0 + base) = *(const float4*)(state + base);
  } else {
    // ================= role C: out1 one-hot rows q < 256 ================
    const int i3 = blk - 1536;     // 0..1023
    const int b = i3 >> 5, qg = i3 & 31;
    if (t < 320) {
#pragma unroll
      for (int k = 0; k < 8; ++k) {
        const int q = qg * 8 + k;
        float4 o = make_float4(0.f, 0.f, 0.f, 0.f);
        if ((q >> 2) == t) {
          const int comp = q & 3;
          if (comp == 0) o.x = 1.f; else if (comp == 1) o.y = 1.f;
          else if (comp == 2) o.z = 1.f; else o.w = 1.f;
        }
        *(float4*)(out1 + ((size_t)(b * 512 + q)) * 1280 + t * 4) = o;
      }
    }
  }
}

extern "C" void kernel_launch(void* const* d_in, const int* in_sizes, int n_in,
                              void* d_out, int out_size, void* d_ws, size_t ws_size,
                              hipStream_t stream) {
  const float* state = (const float*)d_in[0];
  const float* obs0  = (const float*)d_in[1];
  const float* obs1  = (const float*)d_in[2];
  const float* obs2  = (const float*)d_in[3];
  const float* Q     = (const float*)d_in[4];
  const float* Wq    = (const float*)d_in[5];
  const float* bq    = (const float*)d_in[6];
  const float* Wk    = (const float*)d_in[7];
  // d_in[8] = bk: cancels in the 4-way softmax (shift invariance), unused.

  float* out0 = (float*)d_out;                       // new_state [32,256,512]
  float* out1 = out0 + (size_t)32 * 256 * 512;       // atten [32,512,1280]

  float* ws  = (float*)d_ws;
  float* u   = ws;              // 65536
  float* v   = u + 65536;       // 8192
  float* wu2 = v + 8192;        // 524288
  float* wv  = wu2 + 524288;    // 65536
  float* pws = wv + 65536;      // 720896 (16*32*2*704)

  k_uv<<<288, 256, 0, stream>>>(Q, Wq, bq, u, v);
  k_w<<<dim3(256, 2), 256, 0, stream>>>(Wk, u, v, wu2, wv);
  k_part<<<dim3(16, 2, 32), 512, 0, stream>>>(state, obs0, obs1, obs2, wu2, wv, pws);
  k_out<<<2560, 512, 0, stream>>>(state, obs0, obs1, obs2, pws, out0, out1);
}